// Round 10
// baseline (87042.847 us; speedup 1.0000x reference)
//
#include <hip/hip_runtime.h>
#include <hip/hip_bf16.h>
#include <cstdint>
#include <cstddef>

#define D    768
#define G3   2304
#define BS   64
#define SEQ  300
#define TDEC 100
#define TCH  25          // encoder gi chunk length (12 chunks of 25)
#define NCH  12
#define NBLK 512         // encoder persistent grid: 512 blocks x 256 thr
#define NH   (D * 64)    // one h-state buffer (fp32 elems)

#define BAR_WORDS 2048   // EF: enc full [0..511] | EN: enc narrow [512..703]

typedef unsigned int u32;
typedef unsigned long long u64;
typedef unsigned short u16;

__device__ __forceinline__ float sigf(float x) { return 1.0f / (1.0f + __expf(-x)); }
__device__ __forceinline__ float tanhfast(float x) {
    float e = __expf(2.0f * x);
    return 1.0f - 2.0f / (e + 1.0f);
}
__device__ __forceinline__ void bf2x(u32 u, float& a, float& b) {
    union { u32 i; float f; } xx, yy;
    xx.i = u << 16; yy.i = u & 0xffff0000u; a = xx.f; b = yy.f;
}
__device__ __forceinline__ float bfu16(u16 v) {
    union { u32 i; float f; } c; c.i = ((u32)v) << 16; return c.f;
}

#define DOT4(acc, wv, x0, x1, x2, x3) \
    acc = fmaf((wv).x,(x0), fmaf((wv).y,(x1), fmaf((wv).z,(x2), fmaf((wv).w,(x3),(acc)))))

// ---------- coherent (MALL-level) access helpers (proven rounds 2-9) ----------
__device__ __forceinline__ void stG(float* p, float v) {
    __hip_atomic_store(p, v, __ATOMIC_RELAXED, __HIP_MEMORY_SCOPE_AGENT);
}
__device__ __forceinline__ void stG64(u64* p, u64 v) {
    __hip_atomic_store(p, v, __ATOMIC_RELAXED, __HIP_MEMORY_SCOPE_AGENT);
}
__device__ __forceinline__ u32 ldGu(const u32* p) {
    return __hip_atomic_load(p, __ATOMIC_RELAXED, __HIP_MEMORY_SCOPE_AGENT);
}
__device__ __forceinline__ void st_ag(u32* p, u32 v) {
    __hip_atomic_store(p, v, __ATOMIC_RELAXED, __HIP_MEMORY_SCOPE_AGENT);
}
__device__ __forceinline__ u32 ld_ag(const u32* p) {
    return __hip_atomic_load(p, __ATOMIC_RELAXED, __HIP_MEMORY_SCOPE_AGENT);
}
__device__ __forceinline__ u32 f2bfu(float f) {
    __hip_bfloat16 h = __float2bfloat16(f);
    unsigned short s; __builtin_memcpy(&s, &h, 2); return (u32)s;
}
__device__ __forceinline__ float bfsel(u32 w, int sh) {
    union { u32 i; float f; } u; u.i = ((w >> sh) & 0xffffu) << 16; return u.f;
}

// ---------------- FLAG-BROADCAST barriers (r8, encoder only) ----------------
__device__ __forceinline__ void bar_all(u32* F, u32 idx) {
    __builtin_amdgcn_fence(__ATOMIC_RELEASE, "workgroup");
    __syncthreads();
    const int tid = threadIdx.x;
    if (tid == 0) st_ag(&F[blockIdx.x], idx);
    while (ld_ag(&F[tid]) < idx) __builtin_amdgcn_s_sleep(8);
    while (ld_ag(&F[tid + 256]) < idx) __builtin_amdgcn_s_sleep(8);
    __syncthreads();
}
__device__ __forceinline__ void bar_192(u32* F, u32 idx) {
    __builtin_amdgcn_fence(__ATOMIC_RELEASE, "workgroup");
    __syncthreads();
    const int tid = threadIdx.x;
    if (tid == 0) st_ag(&F[blockIdx.x], idx);
    if (tid < 192) { while (ld_ag(&F[tid]) < idx) __builtin_amdgcn_s_sleep(8); }
    __syncthreads();
}

// ---------------- kPrep: init enc h0 + zero barrier words ----------------
__global__ __launch_bounds__(256) void kPrep(
    float* __restrict__ hSeq0, u32* __restrict__ barW)
{
    const int TOT = NH + BAR_WORDS;
    const int stride = gridDim.x * blockDim.x;
    for (int u = blockIdx.x * blockDim.x + threadIdx.x; u < TOT; u += stride) {
        if (u < NH) hSeq0[u] = 0.0f;
        else barW[u - NH] = 0;
    }
}

// ---------------- gi tile (unchanged) ----------------
__device__ __forceinline__ void gi_tile(
    const float* __restrict__ x, const float* __restrict__ Wih,
    __hip_bfloat16* __restrict__ giB, float* __restrict__ As, float* __restrict__ Bs,
    int m0, int tc, int t)
{
    const int tid = threadIdx.x;
    const int lr = tid >> 2;
    const int lk = (tid & 3) * 4;
    const int tm = (tid >> 4) * 4;
    const int tn = (tid & 15) * 4;
    const float tf = (float)t;

    float acc[4][4];
    #pragma unroll
    for (int i = 0; i < 4; ++i)
        #pragma unroll
        for (int j = 0; j < 4; ++j) acc[i][j] = 0.f;

    for (int kc = 0; kc < D; kc += 16) {
        const float4 a4 = *(const float4*)(Wih + (size_t)(m0 + lr) * D + kc + lk);
        float4 b4 = *(const float4*)(x + ((size_t)lr * SEQ + t) * D + kc + lk);
        const int i0 = (kc + lk) >> 1;
        const float dv0 = __expf(-0.0239852614f * (float)i0);
        const float dv1 = __expf(-0.0239852614f * (float)(i0 + 1));
        float s0, c0, s1, c1;
        __sincosf(tf * dv0, &s0, &c0);
        __sincosf(tf * dv1, &s1, &c1);
        b4.x += s0; b4.y += c0; b4.z += s1; b4.w += c1;
        As[(lk + 0) * 64 + lr] = a4.x; As[(lk + 1) * 64 + lr] = a4.y;
        As[(lk + 2) * 64 + lr] = a4.z; As[(lk + 3) * 64 + lr] = a4.w;
        Bs[(lk + 0) * 64 + lr] = b4.x; Bs[(lk + 1) * 64 + lr] = b4.y;
        Bs[(lk + 2) * 64 + lr] = b4.z; Bs[(lk + 3) * 64 + lr] = b4.w;
        __syncthreads();
        #pragma unroll
        for (int k = 0; k < 16; ++k) {
            const float4 av = *(const float4*)(As + k * 64 + tm);
            const float4 bv = *(const float4*)(Bs + k * 64 + tn);
            acc[0][0] = fmaf(av.x, bv.x, acc[0][0]); acc[0][1] = fmaf(av.x, bv.y, acc[0][1]);
            acc[0][2] = fmaf(av.x, bv.z, acc[0][2]); acc[0][3] = fmaf(av.x, bv.w, acc[0][3]);
            acc[1][0] = fmaf(av.y, bv.x, acc[1][0]); acc[1][1] = fmaf(av.y, bv.y, acc[1][1]);
            acc[1][2] = fmaf(av.y, bv.z, acc[1][2]); acc[1][3] = fmaf(av.y, bv.w, acc[1][3]);
            acc[2][0] = fmaf(av.z, bv.x, acc[2][0]); acc[2][1] = fmaf(av.z, bv.y, acc[2][1]);
            acc[2][2] = fmaf(av.z, bv.z, acc[2][2]); acc[2][3] = fmaf(av.z, bv.w, acc[2][3]);
            acc[3][0] = fmaf(av.w, bv.x, acc[3][0]); acc[3][1] = fmaf(av.w, bv.y, acc[3][1]);
            acc[3][2] = fmaf(av.w, bv.z, acc[3][2]); acc[3][3] = fmaf(av.w, bv.w, acc[3][3]);
        }
        __syncthreads();
    }
    #pragma unroll
    for (int i = 0; i < 4; ++i) {
        u32 lo = f2bfu(acc[i][0]) | (f2bfu(acc[i][1]) << 16);
        u32 hi = f2bfu(acc[i][2]) | (f2bfu(acc[i][3]) << 16);
        u64 v = ((u64)hi << 32) | (u64)lo;
        stG64((u64*)(giB + ((size_t)tc * G3 + m0 + tm + i) * 64 + tn), v);
    }
}

// ---------------- encoder recurrence step (unchanged) ----------------
__device__ __forceinline__ void enc_step(
    const __hip_bfloat16* __restrict__ giT, const float* __restrict__ Whh,
    const float* __restrict__ bih, const float* __restrict__ bhh,
    const float* __restrict__ hrd, float* __restrict__ hwr,
    __hip_bfloat16* __restrict__ encB, int t, float* __restrict__ lds_h)
{
    const int tid = threadIdx.x;
    const int b   = tid & 63;
    const int jw  = __builtin_amdgcn_readfirstlane((int)(blockIdx.x * 4 + (tid >> 6)));

    const float* whr = Whh + (size_t)jw * D;
    const float* whz = Whh + (size_t)(768 + jw) * D;
    const float* whn = Whh + (size_t)(1536 + jw) * D;

    float ahr = 0.f, ahz = 0.f, ahn = 0.f;
    for (int kc = 0; kc < D; kc += 64) {
        const float4* gh = (const float4*)(hrd + kc * 64);
        float4* lh = (float4*)lds_h;
        #pragma unroll
        for (int it = 0; it < 4; ++it) lh[tid + 256 * it] = gh[tid + 256 * it];
        __syncthreads();
        #pragma unroll
        for (int kk = 0; kk < 64; kk += 4) {
            const float4 v3 = *(const float4*)(whr + kc + kk);
            const float4 v4 = *(const float4*)(whz + kc + kk);
            const float4 v5 = *(const float4*)(whn + kc + kk);
            const float h0 = lds_h[(kk + 0) * 64 + b];
            const float h1 = lds_h[(kk + 1) * 64 + b];
            const float h2 = lds_h[(kk + 2) * 64 + b];
            const float h3 = lds_h[(kk + 3) * 64 + b];
            DOT4(ahr, v3, h0, h1, h2, h3);
            DOT4(ahz, v4, h0, h1, h2, h3);
            DOT4(ahn, v5, h0, h1, h2, h3);
        }
        __syncthreads();
    }
    const u32* gp = (const u32*)giT;
    const int bo = b >> 1, sh = (b & 1) << 4;
    const u32 w0 = ldGu(gp + (size_t)jw * 32 + bo);
    const u32 w1 = ldGu(gp + (size_t)(768 + jw) * 32 + bo);
    const u32 w2 = ldGu(gp + (size_t)(1536 + jw) * 32 + bo);
    const float gir = bfsel(w0, sh);
    const float giz = bfsel(w1, sh);
    const float gin = bfsel(w2, sh);
    const float r = sigf(gir + bih[jw] + ahr + bhh[jw]);
    const float z = sigf(giz + bih[768 + jw] + ahz + bhh[768 + jw]);
    const float n = tanhfast(gin + bih[1536 + jw] + r * (ahn + bhh[1536 + jw]));
    const float ho = hrd[jw * 64 + b];
    const float hn = (1.f - z) * n + z * ho;
    stG(hwr + jw * 64 + b, hn);
    encB[((size_t)b * SEQ + t) * D + jw] = __float2bfloat16(hn);
}

// ---------------- kEncPersist (r8/r9 proven structure) ----------------
__global__ __launch_bounds__(256) void kEncPersist(
    const float* __restrict__ x, const float* __restrict__ eWih,
    const float* __restrict__ eWhh, const float* __restrict__ ebih,
    const float* __restrict__ ebhh, __hip_bfloat16* __restrict__ giB,
    float* __restrict__ hSeq, __hip_bfloat16* __restrict__ encB,
    u32* EF, u32* EN)
{
    __shared__ float smem[4096];
    const int bid = blockIdx.x;
    const size_t GSZ = (size_t)TCH * G3 * 64;
    u32 fe = 0, fn = 0;

    for (int job = bid; job < 36 * TCH; job += NBLK)
        gi_tile(x, eWih, giB, smem, smem + 1024, (job % 36) * 64, job / 36, job / 36);
    bar_all(EF, ++fe);

    for (int c = 0; c < NCH; ++c) {
        __hip_bfloat16* gcur = giB + (size_t)(c & 1) * GSZ;
        __hip_bfloat16* gnxt = giB + (size_t)((c + 1) & 1) * GSZ;
        if (bid < 192) {
            for (int tc = 0; tc < TCH; ++tc) {
                const int t = c * TCH + tc;
                __builtin_amdgcn_s_setprio(1);
                enc_step(gcur + (size_t)tc * G3 * 64, eWhh, ebih, ebhh,
                         hSeq + (size_t)t * NH, hSeq + (size_t)(t + 1) * NH, encB, t, smem);
                __builtin_amdgcn_s_setprio(0);
                bar_192(EN, ++fn);
            }
        } else if (c + 1 < NCH) {
            for (int j = bid - 192; j < 36 * TCH; j += 320)
                gi_tile(x, eWih, gnxt, smem, smem + 1024,
                        (j % 36) * 64, j / 36, (c + 1) * TCH + j / 36);
        }
        bar_all(EF, ++fe);
    }
}

// ---------------- kGemmMem (unchanged) ----------------
__global__ __launch_bounds__(256) void kGemmMem(
    const __hip_bfloat16* __restrict__ encB, const float* __restrict__ mW,
    const float* __restrict__ mb, __hip_bfloat16* __restrict__ memB)
{
    __shared__ float As[16 * 64];
    __shared__ float Bs[16 * 64];
    const int tid = threadIdx.x;
    const int m0 = blockIdx.y * 64, n0 = blockIdx.x * 64;
    const int lr = tid >> 2;
    const int lk = (tid & 3) * 4;
    const int tm = (tid >> 4) * 4;
    const int tn = (tid & 15) * 4;

    float acc[4][4];
    #pragma unroll
    for (int i = 0; i < 4; ++i)
        #pragma unroll
        for (int j = 0; j < 4; ++j) acc[i][j] = 0.f;

    for (int kc = 0; kc < D; kc += 16) {
        const uint2 ua = *(const uint2*)(encB + (size_t)(m0 + lr) * D + kc + lk);
        float a0, a1, a2, a3;
        bf2x(ua.x, a0, a1); bf2x(ua.y, a2, a3);
        const float4 b4 = *(const float4*)(mW + (size_t)(n0 + lr) * D + kc + lk);
        As[(lk + 0) * 64 + lr] = a0; As[(lk + 1) * 64 + lr] = a1;
        As[(lk + 2) * 64 + lr] = a2; As[(lk + 3) * 64 + lr] = a3;
        Bs[(lk + 0) * 64 + lr] = b4.x; Bs[(lk + 1) * 64 + lr] = b4.y;
        Bs[(lk + 2) * 64 + lr] = b4.z; Bs[(lk + 3) * 64 + lr] = b4.w;
        __syncthreads();
        #pragma unroll
        for (int k = 0; k < 16; ++k) {
            const float4 av = *(const float4*)(As + k * 64 + tm);
            const float4 bv = *(const float4*)(Bs + k * 64 + tn);
            acc[0][0] = fmaf(av.x, bv.x, acc[0][0]); acc[0][1] = fmaf(av.x, bv.y, acc[0][1]);
            acc[0][2] = fmaf(av.x, bv.z, acc[0][2]); acc[0][3] = fmaf(av.x, bv.w, acc[0][3]);
            acc[1][0] = fmaf(av.y, bv.x, acc[1][0]); acc[1][1] = fmaf(av.y, bv.y, acc[1][1]);
            acc[1][2] = fmaf(av.y, bv.z, acc[1][2]); acc[1][3] = fmaf(av.y, bv.w, acc[1][3]);
            acc[2][0] = fmaf(av.z, bv.x, acc[2][0]); acc[2][1] = fmaf(av.z, bv.y, acc[2][1]);
            acc[2][2] = fmaf(av.z, bv.z, acc[2][2]); acc[2][3] = fmaf(av.z, bv.w, acc[2][3]);
            acc[3][0] = fmaf(av.w, bv.x, acc[3][0]); acc[3][1] = fmaf(av.w, bv.y, acc[3][1]);
            acc[3][2] = fmaf(av.w, bv.z, acc[3][2]); acc[3][3] = fmaf(av.w, bv.w, acc[3][3]);
        }
        __syncthreads();
    }
    const float bb0 = mb[n0 + tn + 0], bb1 = mb[n0 + tn + 1];
    const float bb2 = mb[n0 + tn + 2], bb3 = mb[n0 + tn + 3];
    #pragma unroll
    for (int i = 0; i < 4; ++i) {
        __hip_bfloat16* row = memB + (size_t)(m0 + tm + i) * D + n0 + tn;
        row[0] = __float2bfloat16(acc[i][0] + bb0);
        row[1] = __float2bfloat16(acc[i][1] + bb1);
        row[2] = __float2bfloat16(acc[i][2] + bb2);
        row[3] = __float2bfloat16(acc[i][3] + bb3);
    }
}

// ---------------- kDecB: whole decoder, ONE block per batch sample, ZERO grid sync ----------------
// block b (64 blocks x 1024 threads = 16 waves): h/q/w/ctx in LDS; weights read-only
// (shared via L2 by the 8 same-code blocks per XCD). out[b][t] stored directly.
__global__ __launch_bounds__(1024) void kDecB(
    const float* __restrict__ decWih, const float* __restrict__ dWhh,
    const float* __restrict__ dbih, const float* __restrict__ dbhh,
    const float* __restrict__ qW, const float* __restrict__ qb,
    const float* __restrict__ pW, const float* __restrict__ pb,
    const float* __restrict__ tW, const float* __restrict__ tb,
    const __hip_bfloat16* __restrict__ memB, const __hip_bfloat16* __restrict__ encB,
    float* __restrict__ out)
{
    __shared__ float sh[2][768];     // h ping-pong
    __shared__ float sq[768];
    __shared__ float swl[304];       // softmax numerators
    __shared__ float sctx[768];      // ctx / se
    __shared__ float red[16];
    __shared__ float sinv[1], slast[1];

    const int b    = blockIdx.x;
    const int tid  = threadIdx.x;
    const int lane = tid & 63;
    const int wv   = tid >> 6;       // 0..15

    if (tid < 768) sh[0][tid] = 0.f;
    if (tid == 0) slast[0] = 0.f;

    float pwreg[12];
    #pragma unroll
    for (int i = 0; i < 12; ++i) pwreg[i] = pW[lane + 64 * i];
    const float pbv = pb[0];
    const float tbv = tb[0];
    const u16* mrow0 = (const u16*)(memB + (size_t)b * SEQ * D);
    const u16* erow0 = (const u16*)(encB + (size_t)b * SEQ * D);
    __syncthreads();

    for (int t = 0; t < TDEC; ++t) {
        const float* hO = sh[t & 1];
        float*       hN = sh[(t & 1) ^ 1];
        float hreg[12];
        #pragma unroll
        for (int i = 0; i < 12; ++i) hreg[i] = hO[lane + 64 * i];

        // ---- q[j] = qW[j,:] . h + qb[j] (wave-per-j, lane-split K) ----
        for (int j = wv; j < 768; j += 16) {
            const float* wr = qW + (size_t)j * D;
            float a = 0.f;
            #pragma unroll
            for (int i = 0; i < 12; ++i) a = fmaf(wr[lane + 64 * i], hreg[i], a);
            #pragma unroll
            for (int o = 32; o > 0; o >>= 1) a += __shfl_xor(a, o, 64);
            if (lane == 0) sq[j] = a + qb[j];
        }
        __syncthreads();

        // ---- logits + exp (wave-per-s) ----
        float qreg[12];
        #pragma unroll
        for (int i = 0; i < 12; ++i) qreg[i] = sq[lane + 64 * i];
        float seacc = 0.f;
        for (int s = wv; s < SEQ; s += 16) {
            const u16* mr = mrow0 + (size_t)s * D;
            float lp = 0.f;
            #pragma unroll
            for (int i = 0; i < 12; ++i)
                lp = fmaf(pwreg[i], tanhfast(bfu16(mr[lane + 64 * i]) + qreg[i]), lp);
            #pragma unroll
            for (int o = 32; o > 0; o >>= 1) lp += __shfl_xor(lp, o, 64);
            const float e = __expf(lp + pbv);
            if (lane == 0) swl[s] = e;
            seacc += e;                        // wave-uniform after reduce
        }
        if (lane == 0) red[wv] = seacc;
        __syncthreads();
        if (tid == 0) {
            float ssum = 0.f;
            #pragma unroll
            for (int i = 0; i < 16; ++i) ssum += red[i];
            sinv[0] = 1.f / ssum;
        }
        __syncthreads();

        // ---- ctx[e] = (sum_s w[s] enc[b,s,e]) / se  (thread-per-e) ----
        if (tid < 768) {
            const u16* ec = erow0 + tid;
            float a = 0.f;
            #pragma unroll 4
            for (int s = 0; s < SEQ; ++s)
                a = fmaf(swl[s], bfu16(ec[(size_t)s * D]), a);
            sctx[tid] = a * sinv[0];
        }
        __syncthreads();

        // ---- GRU cell + pred partial (wave-per-j, 6 dots lane-split) ----
        float creg[12];
        #pragma unroll
        for (int i = 0; i < 12; ++i) creg[i] = sctx[lane + 64 * i];
        const float lst = slast[0];
        float pacc = 0.f;
        for (int j = wv; j < 768; j += 16) {
            const float* wc0 = decWih + (size_t)j * 769;           // [0]=W0, 1..768=Wc
            const float* wc1 = decWih + (size_t)(768 + j) * 769;
            const float* wc2 = decWih + (size_t)(1536 + j) * 769;
            const float* wh0 = dWhh + (size_t)j * D;
            const float* wh1 = dWhh + (size_t)(768 + j) * D;
            const float* wh2 = dWhh + (size_t)(1536 + j) * D;
            float ar = 0.f, az = 0.f, an = 0.f, br = 0.f, bz = 0.f, bn = 0.f;
            #pragma unroll
            for (int i = 0; i < 12; ++i) {
                const int k = lane + 64 * i;
                ar = fmaf(wc0[1 + k], creg[i], ar);
                az = fmaf(wc1[1 + k], creg[i], az);
                an = fmaf(wc2[1 + k], creg[i], an);
                br = fmaf(wh0[k], hreg[i], br);
                bz = fmaf(wh1[k], hreg[i], bz);
                bn = fmaf(wh2[k], hreg[i], bn);
            }
            #pragma unroll
            for (int o = 32; o > 0; o >>= 1) {
                ar += __shfl_xor(ar, o, 64);
                az += __shfl_xor(az, o, 64);
                an += __shfl_xor(an, o, 64);
                br += __shfl_xor(br, o, 64);
                bz += __shfl_xor(bz, o, 64);
                bn += __shfl_xor(bn, o, 64);
            }
            if (lane == 0) {
                const float gir = ar + wc0[0] * lst + dbih[j];
                const float giz = az + wc1[0] * lst + dbih[768 + j];
                const float gin = an + wc2[0] * lst + dbih[1536 + j];
                const float r = sigf(gir + br + dbhh[j]);
                const float z = sigf(giz + bz + dbhh[768 + j]);
                const float n = tanhfast(gin + r * (bn + dbhh[1536 + j]));
                const float hn = (1.f - z) * n + z * hO[j];
                hN[j] = hn;
                pacc = fmaf(tW[j], hn, pacc);
            }
        }
        if (lane == 0) red[wv] = pacc;
        __syncthreads();
        if (tid == 0) {
            float p = tbv;
            #pragma unroll
            for (int i = 0; i < 16; ++i) p += red[i];
            out[(size_t)b * TDEC + t] = p;
            slast[0] = p;
        }
        __syncthreads();
    }
}

// ---------------- launch ----------------
extern "C" void kernel_launch(void* const* d_in, const int* in_sizes, int n_in,
                              void* d_out, int out_size, void* d_ws, size_t ws_size,
                              hipStream_t stream) {
    const float* x    = (const float*)d_in[0];
    const float* eWih = (const float*)d_in[1];
    const float* eWhh = (const float*)d_in[2];
    const float* ebih = (const float*)d_in[3];
    const float* ebhh = (const float*)d_in[4];
    const float* dWih = (const float*)d_in[5];
    const float* dWhh = (const float*)d_in[6];
    const float* dbih = (const float*)d_in[7];
    const float* dbhh = (const float*)d_in[8];
    const float* qW   = (const float*)d_in[9];
    const float* qb   = (const float*)d_in[10];
    const float* mW   = (const float*)d_in[11];
    const float* mb   = (const float*)d_in[12];
    const float* pW   = (const float*)d_in[13];
    const float* pb   = (const float*)d_in[14];
    const float* tW   = (const float*)d_in[15];
    const float* tb   = (const float*)d_in[16];
    float* out = (float*)d_out;

    char* w = (char*)d_ws;
    auto alloc = [&](size_t bytes) -> char* {
        char* p = w; w += (bytes + 255) & ~(size_t)255; return p;
    };
    // ~134 MB
    __hip_bfloat16* encB = (__hip_bfloat16*)alloc((size_t)BS * SEQ * D * 2);
    __hip_bfloat16* memB = (__hip_bfloat16*)alloc((size_t)BS * SEQ * D * 2);
    __hip_bfloat16* giB  = (__hip_bfloat16*)alloc((size_t)2 * TCH * G3 * 64 * 2);  // double buffer
    float* hSeq  = (float*)alloc((size_t)(SEQ + 1) * NH * 4);
    u32*   barW  = (u32*)alloc((size_t)BAR_WORDS * 4);
    u32*   EF = barW;            // enc full  [512]
    u32*   EN = barW + 512;      // enc narrow[192]

    kPrep<<<256, 256, 0, stream>>>(hSeq, barW);
    kEncPersist<<<NBLK, 256, 0, stream>>>(x, eWih, eWhh, ebih, ebhh, giB, hSeq, encB, EF, EN);
    kGemmMem<<<dim3(12, 300), 256, 0, stream>>>(encB, mW, mb, memB);
    kDecB<<<64, 1024, 0, stream>>>(dWih, dWhh, dbih, dbhh, qW, qb, pW, pb, tW, tb,
                                   memB, encB, out);
}

// Round 11
// 20278.667 us; speedup vs baseline: 4.2923x; 4.2923x over previous
//
#include <hip/hip_runtime.h>
#include <hip/hip_bf16.h>
#include <cstdint>
#include <cstddef>

#define D    768
#define G3   2304
#define BS   64
#define SEQ  300
#define TDEC 100
#define TCH  25          // encoder gi chunk length (12 chunks of 25)
#define NCH  12
#define NBLK 512         // persistent grid: 512 blocks x 256 thr = 2 blocks/CU
#define NH   (D * 64)    // one h-state buffer (fp32 elems)

// ---- barrier region layout (u32 words; lines 128B apart). Two regions: enc, dec. ----
#define R_SLOW_GRP(g)  ((g) * 32)          // 16 slow group counters (MALL)
#define R_SLOW_TOP     512
#define R_SLOW_GEN0    544
#define R_SLOW_GENL(g) (576 + (g) * 32)    // 16 slow release lines (MALL)
#define R_FA_LARR      1088                // fast A: 8 local-L2 arrival lines (+g*32)
#define R_FA_GENL      1344                // fast A: 8 MALL release lines (+g*32)
#define R_FA_TOP       1600
#define R_FA_GEN0      1632
#define R_FB_LARR      1664                // fast B (enc steps): local arrivals
#define R_FB_GENL      1920
#define R_FB_TOP       2176
#define R_FB_GEN0      2208
#define R_PROBE(g)     (2240 + (g) * 32)   // census probe lines (local-L2)
#define R_VOTE         2496
#define R_SIZE         4096                // u32 words per region

typedef unsigned int u32;
typedef unsigned long long u64;

__device__ __forceinline__ float sigf(float x) { return 1.0f / (1.0f + __expf(-x)); }
__device__ __forceinline__ float tanhfast(float x) {
    float e = __expf(2.0f * x);
    return 1.0f - 2.0f / (e + 1.0f);
}
__device__ __forceinline__ void bf2x(u32 u, float& a, float& b) {
    union { u32 i; float f; } xx, yy;
    xx.i = u << 16; yy.i = u & 0xffff0000u; a = xx.f; b = yy.f;
}

#define DOT4(acc, wv, x0, x1, x2, x3) \
    acc = fmaf((wv).x,(x0), fmaf((wv).y,(x1), fmaf((wv).z,(x2), fmaf((wv).w,(x3),(acc)))))

// ---------- coherent (MALL-level) access helpers (proven rounds 2-9) ----------
__device__ __forceinline__ void stG(float* p, float v) {
    __hip_atomic_store(p, v, __ATOMIC_RELAXED, __HIP_MEMORY_SCOPE_AGENT);
}
__device__ __forceinline__ void stG64(u64* p, u64 v) {
    __hip_atomic_store(p, v, __ATOMIC_RELAXED, __HIP_MEMORY_SCOPE_AGENT);
}
__device__ __forceinline__ float ldGf(const float* p) {
    return __hip_atomic_load(p, __ATOMIC_RELAXED, __HIP_MEMORY_SCOPE_AGENT);
}
__device__ __forceinline__ u32 ldGu(const u32* p) {
    return __hip_atomic_load(p, __ATOMIC_RELAXED, __HIP_MEMORY_SCOPE_AGENT);
}
__device__ __forceinline__ u32 f2bfu(float f) {
    __hip_bfloat16 h = __float2bfloat16(f);
    unsigned short s; __builtin_memcpy(&s, &h, 2); return (u32)s;
}
__device__ __forceinline__ float bfsel(u32 w, int sh) {
    union { u32 i; float f; } u; u.i = ((w >> sh) & 0xffffu) << 16; return u.f;
}

// ---------- scoped atomic helpers (pure HIP, no inline asm) ----------
__device__ __forceinline__ u32 add_wg(u32* p, u32 v) {     // executes at local (XCD) L2
    return __hip_atomic_fetch_add(p, v, __ATOMIC_RELAXED, __HIP_MEMORY_SCOPE_WORKGROUP);
}
__device__ __forceinline__ u32 add_ag(u32* p, u32 v) {     // executes at MALL
    return __hip_atomic_fetch_add(p, v, __ATOMIC_RELAXED, __HIP_MEMORY_SCOPE_AGENT);
}
__device__ __forceinline__ void st_ag(u32* p, u32 v) {
    __hip_atomic_store(p, v, __ATOMIC_RELAXED, __HIP_MEMORY_SCOPE_AGENT);
}
__device__ __forceinline__ u32 ld_ag(const u32* p) {
    return __hip_atomic_load(p, __ATOMIC_RELAXED, __HIP_MEMORY_SCOPE_AGENT);
}

// nontemporal bf16x4 load (8B) — keep streamed attn data from evicting L2-resident weights
__device__ __forceinline__ uint2 ldnt2(const __hip_bfloat16* p) {
    u64 v = __builtin_nontemporal_load((const u64*)p);
    uint2 r; r.x = (u32)v; r.y = (u32)(v >> 32); return r;
}

// ---------------- SLOW barrier: MALL tree (proven fallback) ----------------
__device__ __forceinline__ void bar_slow(u32* B, u32 idx) {
    __builtin_amdgcn_fence(__ATOMIC_RELEASE, "workgroup");
    __syncthreads();
    if (threadIdx.x == 0) {
        const u32 g = blockIdx.x >> 5;
        u32 old = add_ag(&B[R_SLOW_GRP(g)], 1u);
        if (old == idx * 32u - 1u) {
            u32 o2 = add_ag(&B[R_SLOW_TOP], 1u);
            if (o2 == idx * 16u - 1u) {
                st_ag(&B[R_SLOW_GEN0], idx);
            } else {
                while (ld_ag(&B[R_SLOW_GEN0]) < idx) __builtin_amdgcn_s_sleep(4);
            }
            st_ag(&B[R_SLOW_GENL(g)], idx);
        } else {
            while (ld_ag(&B[R_SLOW_GENL(g)]) < idx) __builtin_amdgcn_s_sleep(8);
        }
    }
    __syncthreads();
}

// ---------------- FAST barrier: local-L2 arrival + 8-leader MALL release ----------------
__device__ __forceinline__ void bar_fast(u32* R, int larr, int genl, int top, int gen0,
                                         u32 idx, u32 perClass) {
    __builtin_amdgcn_fence(__ATOMIC_RELEASE, "workgroup");
    __syncthreads();
    if (threadIdx.x == 0) {
        const int g = blockIdx.x & 7;
        u32 old = add_wg(&R[larr + g * 32], 1u);
        if (old == idx * perClass - 1u) {          // last arriver of this class
            u32 o2 = add_ag(&R[top], 1u);
            if (o2 == idx * 8u - 1u) {
                st_ag(&R[gen0], idx);
            } else {
                while (ld_ag(&R[gen0]) < idx) __builtin_amdgcn_s_sleep(2);
            }
            st_ag(&R[genl + g * 32], idx);
        } else {
            while (ld_ag(&R[genl + g * 32]) < idx) __builtin_amdgcn_s_sleep(4);
        }
    }
    __syncthreads();
}
#define BAR_FA(R, i, n) bar_fast((R), R_FA_LARR, R_FA_GENL, R_FA_TOP, R_FA_GEN0, (i), (n))
#define BAR_FB(R, i, n) bar_fast((R), R_FB_LARR, R_FB_GENL, R_FB_TOP, R_FB_GEN0, (i), (n))

// ---------------- census: two fetch_add rounds; vote yes iff round-2 old >= 64 ----------------
__device__ __forceinline__ u32 censusRun(u32* R, u32* sflag) {
    if (threadIdx.x == 0) add_wg(&R[R_PROBE(blockIdx.x & 7)], 1u);
    bar_slow(R, 1);
    if (threadIdx.x == 0) {
        u32 old = add_wg(&R[R_PROBE(blockIdx.x & 7)], 1u);
        add_ag(&R[R_VOTE], (old >= (u32)(NBLK / 8)) ? 1u : 0u);
    }
    bar_slow(R, 2);
    if (threadIdx.x == 0) *sflag = (ld_ag(&R[R_VOTE]) == (u32)NBLK) ? 1u : 0u;
    __syncthreads();
    return *sflag;
}

// ---------------- kPrep: dec_Wih split, init states, ZERO-seed ctxC/seC, zero barriers ----------------
__global__ __launch_bounds__(256) void kPrep(
    const float* __restrict__ decWih,
    float* __restrict__ Wc, float* __restrict__ W0,
    float* __restrict__ hSeq0, float* __restrict__ hDs0,
    float* __restrict__ lastP, float* __restrict__ ctxC, float* __restrict__ seC,
    u32* __restrict__ barW)
{
    const int NW = G3 * 769;
    const int NB = 2 * R_SIZE;
    const int NCTX = TDEC * BS * D;       // 4,915,200
    const int NSE  = TDEC * 64;
    const int TOT = NW + 2 * NH + 64 + NCTX + NSE + NB;
    const int stride = gridDim.x * blockDim.x;
    for (int u = blockIdx.x * blockDim.x + threadIdx.x; u < TOT; u += stride) {
        if (u < NW) {
            int g = u / 769; int c = u % 769;
            float w = decWih[u];
            if (c == 0) W0[g] = w; else Wc[(size_t)g * D + (c - 1)] = w;
        } else if (u < NW + NH) {
            hSeq0[u - NW] = 0.0f;
        } else if (u < NW + 2 * NH) {
            hDs0[u - NW - NH] = 0.0f;
        } else if (u < NW + 2 * NH + 64) {
            lastP[u - NW - 2 * NH] = 0.0f;
        } else if (u < NW + 2 * NH + 64 + NCTX) {
            ctxC[u - NW - 2 * NH - 64] = 0.0f;        // attn atomicAdds into this
        } else if (u < NW + 2 * NH + 64 + NCTX + NSE) {
            seC[u - NW - 2 * NH - 64 - NCTX] = 0.0f;
        } else {
            barW[u - NW - 2 * NH - 64 - NCTX - NSE] = 0;
        }
    }
}

// ---------------- gi tile (round-5 body) ----------------
__device__ __forceinline__ void gi_tile(
    const float* __restrict__ x, const float* __restrict__ Wih,
    __hip_bfloat16* __restrict__ giB, float* __restrict__ As, float* __restrict__ Bs,
    int m0, int tc, int t)
{
    const int tid = threadIdx.x;
    const int lr = tid >> 2;
    const int lk = (tid & 3) * 4;
    const int tm = (tid >> 4) * 4;
    const int tn = (tid & 15) * 4;
    const float tf = (float)t;

    float acc[4][4];
    #pragma unroll
    for (int i = 0; i < 4; ++i)
        #pragma unroll
        for (int j = 0; j < 4; ++j) acc[i][j] = 0.f;

    for (int kc = 0; kc < D; kc += 16) {
        const float4 a4 = *(const float4*)(Wih + (size_t)(m0 + lr) * D + kc + lk);
        float4 b4 = *(const float4*)(x + ((size_t)lr * SEQ + t) * D + kc + lk);
        const int i0 = (kc + lk) >> 1;
        const float dv0 = __expf(-0.0239852614f * (float)i0);
        const float dv1 = __expf(-0.0239852614f * (float)(i0 + 1));
        float s0, c0, s1, c1;
        __sincosf(tf * dv0, &s0, &c0);
        __sincosf(tf * dv1, &s1, &c1);
        b4.x += s0; b4.y += c0; b4.z += s1; b4.w += c1;
        As[(lk + 0) * 64 + lr] = a4.x; As[(lk + 1) * 64 + lr] = a4.y;
        As[(lk + 2) * 64 + lr] = a4.z; As[(lk + 3) * 64 + lr] = a4.w;
        Bs[(lk + 0) * 64 + lr] = b4.x; Bs[(lk + 1) * 64 + lr] = b4.y;
        Bs[(lk + 2) * 64 + lr] = b4.z; Bs[(lk + 3) * 64 + lr] = b4.w;
        __syncthreads();
        #pragma unroll
        for (int k = 0; k < 16; ++k) {
            const float4 av = *(const float4*)(As + k * 64 + tm);
            const float4 bv = *(const float4*)(Bs + k * 64 + tn);
            acc[0][0] = fmaf(av.x, bv.x, acc[0][0]); acc[0][1] = fmaf(av.x, bv.y, acc[0][1]);
            acc[0][2] = fmaf(av.x, bv.z, acc[0][2]); acc[0][3] = fmaf(av.x, bv.w, acc[0][3]);
            acc[1][0] = fmaf(av.y, bv.x, acc[1][0]); acc[1][1] = fmaf(av.y, bv.y, acc[1][1]);
            acc[1][2] = fmaf(av.y, bv.z, acc[1][2]); acc[1][3] = fmaf(av.y, bv.w, acc[1][3]);
            acc[2][0] = fmaf(av.z, bv.x, acc[2][0]); acc[2][1] = fmaf(av.z, bv.y, acc[2][1]);
            acc[2][2] = fmaf(av.z, bv.z, acc[2][2]); acc[2][3] = fmaf(av.z, bv.w, acc[2][3]);
            acc[3][0] = fmaf(av.w, bv.x, acc[3][0]); acc[3][1] = fmaf(av.w, bv.y, acc[3][1]);
            acc[3][2] = fmaf(av.w, bv.z, acc[3][2]); acc[3][3] = fmaf(av.w, bv.w, acc[3][3]);
        }
        __syncthreads();
    }
    #pragma unroll
    for (int i = 0; i < 4; ++i) {
        u32 lo = f2bfu(acc[i][0]) | (f2bfu(acc[i][1]) << 16);
        u32 hi = f2bfu(acc[i][2]) | (f2bfu(acc[i][3]) << 16);
        u64 v = ((u64)hi << 32) | (u64)lo;
        stG64((u64*)(giB + ((size_t)tc * G3 + m0 + tm + i) * 64 + tn), v);
    }
}

// ---------------- encoder recurrence step (round-5 body) ----------------
__device__ __forceinline__ void enc_step(
    const __hip_bfloat16* __restrict__ giT, const float* __restrict__ Whh,
    const float* __restrict__ bih, const float* __restrict__ bhh,
    const float* __restrict__ hrd, float* __restrict__ hwr,
    __hip_bfloat16* __restrict__ encB, int t, float* __restrict__ lds_h)
{
    const int tid = threadIdx.x;
    const int b   = tid & 63;
    const int jw  = __builtin_amdgcn_readfirstlane((int)(blockIdx.x * 4 + (tid >> 6)));

    const float* whr = Whh + (size_t)jw * D;
    const float* whz = Whh + (size_t)(768 + jw) * D;
    const float* whn = Whh + (size_t)(1536 + jw) * D;

    float ahr = 0.f, ahz = 0.f, ahn = 0.f;
    for (int kc = 0; kc < D; kc += 64) {
        const float4* gh = (const float4*)(hrd + kc * 64);
        float4* lh = (float4*)lds_h;
        #pragma unroll
        for (int it = 0; it < 4; ++it) lh[tid + 256 * it] = gh[tid + 256 * it];
        __syncthreads();
        #pragma unroll
        for (int kk = 0; kk < 64; kk += 4) {
            const float4 v3 = *(const float4*)(whr + kc + kk);
            const float4 v4 = *(const float4*)(whz + kc + kk);
            const float4 v5 = *(const float4*)(whn + kc + kk);
            const float h0 = lds_h[(kk + 0) * 64 + b];
            const float h1 = lds_h[(kk + 1) * 64 + b];
            const float h2 = lds_h[(kk + 2) * 64 + b];
            const float h3 = lds_h[(kk + 3) * 64 + b];
            DOT4(ahr, v3, h0, h1, h2, h3);
            DOT4(ahz, v4, h0, h1, h2, h3);
            DOT4(ahn, v5, h0, h1, h2, h3);
        }
        __syncthreads();
    }
    const u32* gp = (const u32*)giT;
    const int bo = b >> 1, sh = (b & 1) << 4;
    const u32 w0 = ldGu(gp + (size_t)jw * 32 + bo);
    const u32 w1 = ldGu(gp + (size_t)(768 + jw) * 32 + bo);
    const u32 w2 = ldGu(gp + (size_t)(1536 + jw) * 32 + bo);
    const float gir = bfsel(w0, sh);
    const float giz = bfsel(w1, sh);
    const float gin = bfsel(w2, sh);
    const float r = sigf(gir + bih[jw] + ahr + bhh[jw]);
    const float z = sigf(giz + bih[768 + jw] + ahz + bhh[768 + jw]);
    const float n = tanhfast(gin + bih[1536 + jw] + r * (ahn + bhh[1536 + jw]));
    const float ho = hrd[jw * 64 + b];
    const float hn = (1.f - z) * n + z * ho;
    stG(hwr + jw * 64 + b, hn);
    encB[((size_t)b * SEQ + t) * D + jw] = __float2bfloat16(hn);
}

// ---------------- kEncPersist (r7 structure) ----------------
__global__ __launch_bounds__(256) void kEncPersist(
    const float* __restrict__ x, const float* __restrict__ eWih,
    const float* __restrict__ eWhh, const float* __restrict__ ebih,
    const float* __restrict__ ebhh, __hip_bfloat16* __restrict__ giB,
    float* __restrict__ hSeq, __hip_bfloat16* __restrict__ encB, u32* R)
{
    __shared__ float smem[4096];
    __shared__ u32 sflag;
    const u32 fast = censusRun(R, &sflag);
    const int bid = blockIdx.x;
    const size_t GSZ = (size_t)TCH * G3 * 64;
    u32 si = 2, fE = 0, fS = 0;

    for (int job = bid; job < 36 * TCH; job += NBLK)
        gi_tile(x, eWih, giB, smem, smem + 1024, (job % 36) * 64, job / 36, job / 36);
    if (fast) BAR_FA(R, ++fE, 64); else bar_slow(R, ++si);

    for (int c = 0; c < NCH; ++c) {
        __hip_bfloat16* gcur = giB + (size_t)(c & 1) * GSZ;
        __hip_bfloat16* gnxt = giB + (size_t)((c + 1) & 1) * GSZ;
        if (fast) {
            if (bid < 192) {
                for (int tc = 0; tc < TCH; ++tc) {
                    const int t = c * TCH + tc;
                    enc_step(gcur + (size_t)tc * G3 * 64, eWhh, ebih, ebhh,
                             hSeq + (size_t)t * NH, hSeq + (size_t)(t + 1) * NH, encB, t, smem);
                    BAR_FB(R, ++fS, 24);      // only the 192 step blocks
                }
            } else if (c + 1 < NCH) {
                for (int j = bid - 192; j < 36 * TCH; j += 320)
                    gi_tile(x, eWih, gnxt, smem, smem + 1024,
                            (j % 36) * 64, j / 36, (c + 1) * TCH + j / 36);
            }
            BAR_FA(R, ++fE, 64);              // chunk seal: all 512
        } else {
            for (int tc = 0; tc < TCH; ++tc) {
                const int t = c * TCH + tc;
                if (bid < 192)
                    enc_step(gcur + (size_t)tc * G3 * 64, eWhh, ebih, ebhh,
                             hSeq + (size_t)t * NH, hSeq + (size_t)(t + 1) * NH, encB, t, smem);
                bar_slow(R, ++si);
            }
            if (c + 1 < NCH) {
                for (int job = bid; job < 36 * TCH; job += NBLK)
                    gi_tile(x, eWih, gnxt, smem, smem + 1024,
                            (job % 36) * 64, job / 36, (c + 1) * TCH + job / 36);
                bar_slow(R, ++si);
            }
        }
    }
}

// ---------------- kGemmMem (unchanged) ----------------
__global__ __launch_bounds__(256) void kGemmMem(
    const __hip_bfloat16* __restrict__ encB, const float* __restrict__ mW,
    const float* __restrict__ mb, __hip_bfloat16* __restrict__ memB)
{
    __shared__ float As[16 * 64];
    __shared__ float Bs[16 * 64];
    const int tid = threadIdx.x;
    const int m0 = blockIdx.y * 64, n0 = blockIdx.x * 64;
    const int lr = tid >> 2;
    const int lk = (tid & 3) * 4;
    const int tm = (tid >> 4) * 4;
    const int tn = (tid & 15) * 4;

    float acc[4][4];
    #pragma unroll
    for (int i = 0; i < 4; ++i)
        #pragma unroll
        for (int j = 0; j < 4; ++j) acc[i][j] = 0.f;

    for (int kc = 0; kc < D; kc += 16) {
        const uint2 ua = *(const uint2*)(encB + (size_t)(m0 + lr) * D + kc + lk);
        float a0, a1, a2, a3;
        bf2x(ua.x, a0, a1); bf2x(ua.y, a2, a3);
        const float4 b4 = *(const float4*)(mW + (size_t)(n0 + lr) * D + kc + lk);
        As[(lk + 0) * 64 + lr] = a0; As[(lk + 1) * 64 + lr] = a1;
        As[(lk + 2) * 64 + lr] = a2; As[(lk + 3) * 64 + lr] = a3;
        Bs[(lk + 0) * 64 + lr] = b4.x; Bs[(lk + 1) * 64 + lr] = b4.y;
        Bs[(lk + 2) * 64 + lr] = b4.z; Bs[(lk + 3) * 64 + lr] = b4.w;
        __syncthreads();
        #pragma unroll
        for (int k = 0; k < 16; ++k) {
            const float4 av = *(const float4*)(As + k * 64 + tm);
            const float4 bv = *(const float4*)(Bs + k * 64 + tn);
            acc[0][0] = fmaf(av.x, bv.x, acc[0][0]); acc[0][1] = fmaf(av.x, bv.y, acc[0][1]);
            acc[0][2] = fmaf(av.x, bv.z, acc[0][2]); acc[0][3] = fmaf(av.x, bv.w, acc[0][3]);
            acc[1][0] = fmaf(av.y, bv.x, acc[1][0]); acc[1][1] = fmaf(av.y, bv.y, acc[1][1]);
            acc[1][2] = fmaf(av.y, bv.z, acc[1][2]); acc[1][3] = fmaf(av.y, bv.w, acc[1][3]);
            acc[2][0] = fmaf(av.z, bv.x, acc[2][0]); acc[2][1] = fmaf(av.z, bv.y, acc[2][1]);
            acc[2][2] = fmaf(av.z, bv.z, acc[2][2]); acc[2][3] = fmaf(av.z, bv.w, acc[2][3]);
            acc[3][0] = fmaf(av.w, bv.x, acc[3][0]); acc[3][1] = fmaf(av.w, bv.y, acc[3][1]);
            acc[3][2] = fmaf(av.w, bv.z, acc[3][2]); acc[3][3] = fmaf(av.w, bv.w, acc[3][3]);
        }
        __syncthreads();
    }
    const float bb0 = mb[n0 + tn + 0], bb1 = mb[n0 + tn + 1];
    const float bb2 = mb[n0 + tn + 2], bb3 = mb[n0 + tn + 3];
    #pragma unroll
    for (int i = 0; i < 4; ++i) {
        __hip_bfloat16* row = memB + (size_t)(m0 + tm + i) * D + n0 + tn;
        row[0] = __float2bfloat16(acc[i][0] + bb0);
        row[1] = __float2bfloat16(acc[i][1] + bb1);
        row[2] = __float2bfloat16(acc[i][2] + bb2);
        row[3] = __float2bfloat16(acc[i][3] + bb3);
    }
}

// ---------------- dec_q (r7) ----------------
__device__ __forceinline__ void dec_q(
    const float* __restrict__ qW, const float* __restrict__ qb,
    const float* __restrict__ hrd, float* __restrict__ qTt,
    float* __restrict__ lds_h, float* __restrict__ lds_t)
{
    const int tid = threadIdx.x;
    const int b   = tid & 63;
    const int wv  = tid >> 6;
    const int jw  = __builtin_amdgcn_readfirstlane((int)(blockIdx.x * 4 + wv));
    const float* w = qW + (size_t)jw * D;
    float acc = 0.f;
    for (int kc = 0; kc < D; kc += 64) {
        const float4* gh = (const float4*)(hrd + kc * 64);
        float4* lh = (float4*)lds_h;
        #pragma unroll
        for (int it = 0; it < 4; ++it) lh[tid + 256 * it] = gh[tid + 256 * it];
        __syncthreads();
        #pragma unroll
        for (int kk = 0; kk < 64; kk += 4) {
            const float4 w4 = *(const float4*)(w + kc + kk);
            acc = fmaf(w4.x, lds_h[(kk + 0) * 64 + b], acc);
            acc = fmaf(w4.y, lds_h[(kk + 1) * 64 + b], acc);
            acc = fmaf(w4.z, lds_h[(kk + 2) * 64 + b], acc);
            acc = fmaf(w4.w, lds_h[(kk + 3) * 64 + b], acc);
        }
        __syncthreads();
    }
    lds_t[b * 4 + wv] = acc + qb[jw];
    __syncthreads();
    if (tid < 128) {
        const int bb = tid >> 1, hf = (tid & 1) * 2;
        float2 v; v.x = lds_t[bb * 4 + hf]; v.y = lds_t[bb * 4 + hf + 1];
        u64 uv; __builtin_memcpy(&uv, &v, 8);
        stG64((u64*)(qTt + (size_t)bb * D + blockIdx.x * 4 + hf), uv);
    }
}

// ---------------- dec_attn (r7 body; epilogue = atomicAdd into unique-per-t ctxC/seC) ----------------
__device__ __forceinline__ void dec_attn(
    const float* __restrict__ qTt, const __hip_bfloat16* __restrict__ memB,
    const __hip_bfloat16* __restrict__ encB, const float* __restrict__ pW,
    const float* __restrict__ pb, float* __restrict__ ctxCt, float* __restrict__ seCt,
    float* __restrict__ sm)
{
    const int tid = threadIdx.x;
    const int b  = blockIdx.x & 63;
    const int ch = blockIdx.x >> 6;          // 0..7
    float* s_q  = sm;
    float* s_pw = sm + 768;
    float* s_cx = sm + 1536;
    float* s_se = sm + 2304;
    for (int i = tid; i < 768; i += 256) {
        s_q[i]  = qTt[(size_t)b * D + i];
        s_pw[i] = pW[i];
        s_cx[i] = 0.f;
    }
    if (tid == 0) s_se[0] = 0.f;
    __syncthreads();
    const int lane = tid & 63;
    const int wv   = tid >> 6;
    const int d0_0 = lane * 4, d0_1 = 256 + lane * 4, d0_2 = 512 + lane * 4;
    const float4 qv0 = *(const float4*)(s_q + d0_0);
    const float4 qv1 = *(const float4*)(s_q + d0_1);
    const float4 qv2 = *(const float4*)(s_q + d0_2);
    const float4 pv0 = *(const float4*)(s_pw + d0_0);
    const float4 pv1 = *(const float4*)(s_pw + d0_1);
    const float4 pv2 = *(const float4*)(s_pw + d0_2);
    float cacc[12];
    #pragma unroll
    for (int i = 0; i < 12; ++i) cacc[i] = 0.f;
    float seacc = 0.f;
    const float pbv = pb[0];
    const size_t rowb = (size_t)b * SEQ;
    int s = ch + 8 * wv;
    uint2 mu0, mu1, mu2, eu0, eu1, eu2;
    if (s < SEQ) {
        const __hip_bfloat16* mrow = memB + (rowb + s) * D;
        const __hip_bfloat16* erow = encB + (rowb + s) * D;
        mu0 = ldnt2(mrow + d0_0); mu1 = ldnt2(mrow + d0_1); mu2 = ldnt2(mrow + d0_2);
        eu0 = ldnt2(erow + d0_0); eu1 = ldnt2(erow + d0_1); eu2 = ldnt2(erow + d0_2);
    }
    while (s < SEQ) {
        const int sn = s + 32;
        const bool pf = sn < SEQ;
        uint2 nm0, nm1, nm2, ne0, ne1, ne2;
        if (pf) {
            const __hip_bfloat16* mrow = memB + (rowb + sn) * D;
            const __hip_bfloat16* erow = encB + (rowb + sn) * D;
            nm0 = ldnt2(mrow + d0_0); nm1 = ldnt2(mrow + d0_1); nm2 = ldnt2(mrow + d0_2);
            ne0 = ldnt2(erow + d0_0); ne1 = ldnt2(erow + d0_1); ne2 = ldnt2(erow + d0_2);
        }
        float lp = 0.f;
        float m0, m1, m2, m3;
        bf2x(mu0.x, m0, m1); bf2x(mu0.y, m2, m3);
        lp = fmaf(pv0.x, tanhfast(m0 + qv0.x), lp);
        lp = fmaf(pv0.y, tanhfast(m1 + qv0.y), lp);
        lp = fmaf(pv0.z, tanhfast(m2 + qv0.z), lp);
        lp = fmaf(pv0.w, tanhfast(m3 + qv0.w), lp);
        bf2x(mu1.x, m0, m1); bf2x(mu1.y, m2, m3);
        lp = fmaf(pv1.x, tanhfast(m0 + qv1.x), lp);
        lp = fmaf(pv1.y, tanhfast(m1 + qv1.y), lp);
        lp = fmaf(pv1.z, tanhfast(m2 + qv1.z), lp);
        lp = fmaf(pv1.w, tanhfast(m3 + qv1.w), lp);
        bf2x(mu2.x, m0, m1); bf2x(mu2.y, m2, m3);
        lp = fmaf(pv2.x, tanhfast(m0 + qv2.x), lp);
        lp = fmaf(pv2.y, tanhfast(m1 + qv2.y), lp);
        lp = fmaf(pv2.z, tanhfast(m2 + qv2.z), lp);
        lp = fmaf(pv2.w, tanhfast(m3 + qv2.w), lp);
        #pragma unroll
        for (int o = 32; o > 0; o >>= 1) lp += __shfl_xor(lp, o, 64);
        const float e = __expf(lp + pbv);
        seacc += e;
        float e0, e1, e2, e3;
        bf2x(eu0.x, e0, e1); bf2x(eu0.y, e2, e3);
        cacc[0] = fmaf(e, e0, cacc[0]); cacc[1] = fmaf(e, e1, cacc[1]);
        cacc[2] = fmaf(e, e2, cacc[2]); cacc[3] = fmaf(e, e3, cacc[3]);
        bf2x(eu1.x, e0, e1); bf2x(eu1.y, e2, e3);
        cacc[4] = fmaf(e, e0, cacc[4]); cacc[5] = fmaf(e, e1, cacc[5]);
        cacc[6] = fmaf(e, e2, cacc[6]); cacc[7] = fmaf(e, e3, cacc[7]);
        bf2x(eu2.x, e0, e1); bf2x(eu2.y, e2, e3);
        cacc[8]  = fmaf(e, e0, cacc[8]);  cacc[9]  = fmaf(e, e1, cacc[9]);
        cacc[10] = fmaf(e, e2, cacc[10]); cacc[11] = fmaf(e, e3, cacc[11]);
        if (pf) { mu0 = nm0; mu1 = nm1; mu2 = nm2; eu0 = ne0; eu1 = ne1; eu2 = ne2; }
        s = sn;
    }
    #pragma unroll
    for (int g = 0; g < 3; ++g) {
        const int d0 = g * 256 + lane * 4;
        atomicAdd(&s_cx[d0 + 0], cacc[g * 4 + 0]);
        atomicAdd(&s_cx[d0 + 1], cacc[g * 4 + 1]);
        atomicAdd(&s_cx[d0 + 2], cacc[g * 4 + 2]);
        atomicAdd(&s_cx[d0 + 3], cacc[g * 4 + 3]);
    }
    if (lane == 0) atomicAdd(&s_se[0], seacc);
    __syncthreads();
    // combine folded in: device-scope atomicAdd into zero-seeded unique-per-t buffers.
    // 8 blocks/b x 768 adds, spread over 49K addresses (no hot-line storm).
    for (int i = tid; i < 768; i += 256) atomicAdd(&ctxCt[(size_t)b * D + i], s_cx[i]);
    if (tid == 0) atomicAdd(&seCt[b], s_se[0]);
}

// ---------------- dec_reduce (r7) ----------------
__device__ __forceinline__ void dec_reduce(
    const float* __restrict__ ppt, const float* __restrict__ tb,
    float* __restrict__ lastN, float* __restrict__ out, int t, float* __restrict__ sm)
{
    const int b = blockIdx.x - 448;
    const int tid = threadIdx.x;
    float v = 0.f;
    if (tid < 192) v = ppt[(size_t)b * 192 + tid];
    #pragma unroll
    for (int o = 32; o > 0; o >>= 1) v += __shfl_xor(v, o, 64);
    if ((tid & 63) == 0) sm[tid >> 6] = v;
    __syncthreads();
    if (tid == 0) {
        const float p = sm[0] + sm[1] + sm[2] + sm[3] + tb[0];
        out[(size_t)b * TDEC + t] = p;
        stG(lastN + b, p);
    }
    __syncthreads();
}

// ---------------- dec_cell (r7; reads combined ctxC[t]/seC[t] fresh lines) ----------------
__device__ __forceinline__ void dec_cell(
    const float* __restrict__ Wc, const float* __restrict__ W0,
    const float* __restrict__ dWhh, const float* __restrict__ dbih,
    const float* __restrict__ dbhh, const float* __restrict__ tW,
    const float* __restrict__ ctxFt, const float* __restrict__ seFt,
    const float* __restrict__ lastT, float* __restrict__ ppt,
    const float* __restrict__ hrd, float* __restrict__ hwr,
    float* __restrict__ lds_h, float* __restrict__ lds_c)
{
    const int tid = threadIdx.x;
    const int b   = tid & 63;
    const int q4  = tid >> 6;
    const int jw  = __builtin_amdgcn_readfirstlane((int)(blockIdx.x * 4 + q4));
    const float* whr = dWhh + (size_t)jw * D;
    const float* whz = dWhh + (size_t)(768 + jw) * D;
    const float* whn = dWhh + (size_t)(1536 + jw) * D;
    const float* wcr = Wc + (size_t)jw * D;
    const float* wcz = Wc + (size_t)(768 + jw) * D;
    const float* wcn = Wc + (size_t)(1536 + jw) * D;
    float cir = 0.f, ciz = 0.f, cin_ = 0.f, ahr = 0.f, ahz = 0.f, ahn = 0.f;
    for (int kc = 0; kc < D; kc += 64) {
        const float4* gh = (const float4*)(hrd + kc * 64);
        float4* lh = (float4*)lds_h;
        #pragma unroll
        for (int it = 0; it < 4; ++it) lh[tid + 256 * it] = gh[tid + 256 * it];
        {
            const float4* cp = (const float4*)(ctxFt + (size_t)b * D + kc + q4 * 16);
            const float4 c0 = cp[0], c1 = cp[1], c2 = cp[2], c3 = cp[3];
            const int k0 = q4 * 16;
            lds_c[(k0 +  0) * 64 + b] = c0.x; lds_c[(k0 +  1) * 64 + b] = c0.y;
            lds_c[(k0 +  2) * 64 + b] = c0.z; lds_c[(k0 +  3) * 64 + b] = c0.w;
            lds_c[(k0 +  4) * 64 + b] = c1.x; lds_c[(k0 +  5) * 64 + b] = c1.y;
            lds_c[(k0 +  6) * 64 + b] = c1.z; lds_c[(k0 +  7) * 64 + b] = c1.w;
            lds_c[(k0 +  8) * 64 + b] = c2.x; lds_c[(k0 +  9) * 64 + b] = c2.y;
            lds_c[(k0 + 10) * 64 + b] = c2.z; lds_c[(k0 + 11) * 64 + b] = c2.w;
            lds_c[(k0 + 12) * 64 + b] = c3.x; lds_c[(k0 + 13) * 64 + b] = c3.y;
            lds_c[(k0 + 14) * 64 + b] = c3.z; lds_c[(k0 + 15) * 64 + b] = c3.w;
        }
        __syncthreads();
        #pragma unroll
        for (int kk = 0; kk < 64; kk += 4) {
            const float4 v0 = *(const float4*)(wcr + kc + kk);
            const float4 v1 = *(const float4*)(wcz + kc + kk);
            const float4 v2 = *(const float4*)(wcn + kc + kk);
            const float4 v3 = *(const float4*)(whr + kc + kk);
            const float4 v4 = *(const float4*)(whz + kc + kk);
            const float4 v5 = *(const float4*)(whn + kc + kk);
            const float c0 = lds_c[(kk + 0) * 64 + b];
            const float c1 = lds_c[(kk + 1) * 64 + b];
            const float c2 = lds_c[(kk + 2) * 64 + b];
            const float c3 = lds_c[(kk + 3) * 64 + b];
            const float h0 = lds_h[(kk + 0) * 64 + b];
            const float h1 = lds_h[(kk + 1) * 64 + b];
            const float h2 = lds_h[(kk + 2) * 64 + b];
            const float h3 = lds_h[(kk + 3) * 64 + b];
            DOT4(cir, v0, c0, c1, c2, c3);
            DOT4(ciz, v1, c0, c1, c2, c3);
            DOT4(cin_, v2, c0, c1, c2, c3);
            DOT4(ahr, v3, h0, h1, h2, h3);
            DOT4(ahz, v4, h0, h1, h2, h3);
            DOT4(ahn, v5, h0, h1, h2, h3);
        }
        __syncthreads();
    }
    const float inv = 1.f / seFt[b];
    const float lst = lastT[b];
    const float gir = cir * inv + W0[jw] * lst + dbih[jw];
    const float giz = ciz * inv + W0[768 + jw] * lst + dbih[768 + jw];
    const float gin = cin_ * inv + W0[1536 + jw] * lst + dbih[1536 + jw];
    const float r = sigf(gir + ahr + dbhh[jw]);
    const float z = sigf(giz + ahz + dbhh[768 + jw]);
    const float n = tanhfast(gin + r * (ahn + dbhh[1536 + jw]));
    const float ho = hrd[jw * 64 + b];
    const float hn = (1.f - z) * n + z * ho;
    stG(hwr + jw * 64 + b, hn);

    __syncthreads();
    lds_h[q4 * 64 + b] = tW[jw] * hn;
    __syncthreads();
    if (tid < 64) {
        const float p = lds_h[tid] + lds_h[64 + tid] + lds_h[128 + tid] + lds_h[192 + tid];
        stG(ppt + (size_t)tid * 192 + blockIdx.x, p);
    }
}

// ---------------- kDecPersist: 3 barriers/step (combine folded into attn atomics) ----------------
__global__ __launch_bounds__(256) void kDecPersist(
    const float* __restrict__ Wc, const float* __restrict__ W0,
    const float* __restrict__ dWhh, const float* __restrict__ dbih,
    const float* __restrict__ dbhh, const float* __restrict__ tW,
    const float* __restrict__ tb, const float* __restrict__ qW,
    const float* __restrict__ qb,
    const __hip_bfloat16* __restrict__ memB, const __hip_bfloat16* __restrict__ encB,
    const float* __restrict__ pW, const float* __restrict__ pb,
    float* __restrict__ qTu, float* __restrict__ ctxC, float* __restrict__ seC,
    float* __restrict__ predP, float* __restrict__ lastP,
    float* __restrict__ hDs, float* __restrict__ out, u32* R)
{
    __shared__ float smem[8192];
    __shared__ u32 sflag;
    const u32 fast = censusRun(R, &sflag);
    u32 si = 2, fA = 0;
    for (int t = 0; t < TDEC; ++t) {
        const float* hr = hDs + (size_t)t * NH;
        float*       hw = hDs + (size_t)(t + 1) * NH;
        if (blockIdx.x < 192)
            dec_q(qW, qb, hr, qTu + (size_t)t * BS * D, smem, smem + 4096);
        else if (blockIdx.x >= 448 && t > 0)
            dec_reduce(predP + (size_t)(t - 1) * 64 * 192, tb,
                       lastP + (size_t)t * 64, out, t - 1, smem);
        if (fast) BAR_FA(R, ++fA, 64); else bar_slow(R, ++si);
        dec_attn(qTu + (size_t)t * BS * D, memB, encB, pW, pb,
                 ctxC + (size_t)t * BS * D, seC + (size_t)t * 64, smem);
        if (fast) BAR_FA(R, ++fA, 64); else bar_slow(R, ++si);
        if (blockIdx.x < 192)
            dec_cell(Wc, W0, dWhh, dbih, dbhh, tW,
                     ctxC + (size_t)t * BS * D, seC + (size_t)t * 64,
                     lastP + (size_t)t * 64, predP + (size_t)t * 64 * 192,
                     hr, hw, smem, smem + 4096);
        if (fast) BAR_FA(R, ++fA, 64); else bar_slow(R, ++si);
    }
    if (blockIdx.x >= 448)
        dec_reduce(predP + (size_t)(TDEC - 1) * 64 * 192, tb,
                   lastP + (size_t)TDEC * 64, out, TDEC - 1, smem);
}

// ---------------- launch ----------------
extern "C" void kernel_launch(void* const* d_in, const int* in_sizes, int n_in,
                              void* d_out, int out_size, void* d_ws, size_t ws_size,
                              hipStream_t stream) {
    const float* x    = (const float*)d_in[0];
    const float* eWih = (const float*)d_in[1];
    const float* eWhh = (const float*)d_in[2];
    const float* ebih = (const float*)d_in[3];
    const float* ebhh = (const float*)d_in[4];
    const float* dWih = (const float*)d_in[5];
    const float* dWhh = (const float*)d_in[6];
    const float* dbih = (const float*)d_in[7];
    const float* dbhh = (const float*)d_in[8];
    const float* qW   = (const float*)d_in[9];
    const float* qb   = (const float*)d_in[10];
    const float* mW   = (const float*)d_in[11];
    const float* mb   = (const float*)d_in[12];
    const float* pW   = (const float*)d_in[13];
    const float* pb   = (const float*)d_in[14];
    const float* tW   = (const float*)d_in[15];
    const float* tb   = (const float*)d_in[16];
    float* out = (float*)d_out;

    char* w = (char*)d_ws;
    auto alloc = [&](size_t bytes) -> char* {
        char* p = w; w += (bytes + 255) & ~(size_t)255; return p;
    };
    // total ~205 MB
    float* Wc    = (float*)alloc((size_t)G3 * D * 4);
    float* W0    = (float*)alloc((size_t)G3 * 4);
    __hip_bfloat16* encB = (__hip_bfloat16*)alloc((size_t)BS * SEQ * D * 2);
    __hip_bfloat16* memB = (__hip_bfloat16*)alloc((size_t)BS * SEQ * D * 2);
    __hip_bfloat16* giB  = (__hip_bfloat16*)alloc((size_t)2 * TCH * G3 * 64 * 2);  // double buffer
    float* hSeq  = (float*)alloc((size_t)(SEQ + 1) * NH * 4);
    float* hDs   = (float*)alloc((size_t)(TDEC + 1) * NH * 4);
    float* qTu   = (float*)alloc((size_t)TDEC * BS * D * 4);
    float* ctxC  = (float*)alloc((size_t)TDEC * BS * D * 4);   // zero-seeded; attn atomicAdds
    float* seC   = (float*)alloc((size_t)TDEC * 64 * 4);       // zero-seeded; attn atomicAdds
    float* predP = (float*)alloc((size_t)TDEC * 64 * 192 * 4);
    float* lastP = (float*)alloc((size_t)(TDEC + 1) * 64 * 4);
    u32*   barW  = (u32*)alloc((size_t)2 * R_SIZE * 4);   // region 0 = enc, region 1 = dec

    kPrep<<<512, 256, 0, stream>>>(dWih, Wc, W0, hSeq, hDs, lastP, ctxC, seC, barW);
    kEncPersist<<<NBLK, 256, 0, stream>>>(x, eWih, eWhh, ebih, ebhh, giB, hSeq, encB, barW);
    kGemmMem<<<dim3(12, 300), 256, 0, stream>>>(encB, mW, mb, memB);
    kDecPersist<<<NBLK, 256, 0, stream>>>(Wc, W0, dWhh, dbih, dbhh, tW, tb, qW, qb,
                                          memB, encB, pW, pb, qTu, ctxC, seC,
                                          predP, lastP, hDs, out, barW + R_SIZE);
}